// Round 3
// baseline (323.277 us; speedup 1.0000x reference)
//
#include <hip/hip_runtime.h>

#define N_NODES 50000
#define N_EDGES 400000
#define DIM 128
#define NA 32
#define NEG 0.01f

// ---------------- Kernel A: per-node projection ----------------
// proj[n][a]    = dot(x[n], W[a][0:128])      for a in [0,32)
// proj[n][32+a] = dot(x[n], W[a][128:256])    for a in [0,32)
// Block: 256 threads, 128 nodes (2 per lane). Wave w (0..3) computes
// proj-quarter [16w, 16w+16) for its 128 nodes.
__global__ __launch_bounds__(256) void proj_kernel(const float* __restrict__ x,
                                                   const float* __restrict__ W,
                                                   float* __restrict__ proj) {
    __shared__ float Wl[64 * 128];  // 32 KB: row a64 = concat-split W
    const int t = threadIdx.x;
    for (int i = 0; i < 32; ++i) {
        int idx = i * 256 + t;
        int a = idx >> 7, k = idx & 127;
        Wl[idx] = (a < 32) ? W[a * 256 + k] : W[(a - 32) * 256 + 128 + k];
    }
    __syncthreads();

    const int n0 = blockIdx.x * 128 + (t & 63);
    const int n1 = n0 + 64;
    const int w = t >> 6;
    const int n0c = n0 < N_NODES ? n0 : 0;
    const int n1c = n1 < N_NODES ? n1 : 0;

    const float4* x4 = (const float4*)x;
    float acc0[16], acc1[16];
#pragma unroll
    for (int i = 0; i < 16; ++i) { acc0[i] = 0.f; acc1[i] = 0.f; }

#pragma unroll 1
    for (int kc = 0; kc < 32; ++kc) {
        float4 xv0 = x4[n0c * 32 + kc];
        float4 xv1 = x4[n1c * 32 + kc];
        const float* wbase = &Wl[(w * 16) * 128 + kc * 4];
#pragma unroll
        for (int i = 0; i < 16; ++i) {
            float4 wv = *(const float4*)(wbase + i * 128);  // wave-broadcast
            acc0[i] += xv0.x * wv.x; acc1[i] += xv1.x * wv.x;
            acc0[i] += xv0.y * wv.y; acc1[i] += xv1.y * wv.y;
            acc0[i] += xv0.z * wv.z; acc1[i] += xv1.z * wv.z;
            acc0[i] += xv0.w * wv.w; acc1[i] += xv1.w * wv.w;
        }
    }

    float4* p4 = (float4*)proj;
    if (n0 < N_NODES) {
#pragma unroll
        for (int j = 0; j < 4; ++j)
            p4[n0 * 16 + w * 4 + j] =
                make_float4(acc0[4 * j], acc0[4 * j + 1], acc0[4 * j + 2], acc0[4 * j + 3]);
    }
    if (n1 < N_NODES) {
#pragma unroll
        for (int j = 0; j < 4; ++j)
            p4[n1 * 16 + w * 4 + j] =
                make_float4(acc1[4 * j], acc1[4 * j + 1], acc1[4 * j + 2], acc1[4 * j + 3]);
    }
}

// ---------------- Kernel B v2: anchor-in-registers + prefetch ----------------
// Half-wave (32 lanes) per edge; wave handles edge pair (2p, 2p+1).
// lane a: logit[a] = proj[s][a] + proj[d][32+a] + b_lin[a]
// anchor[q][4a..4a+3] hoisted to 32 float4 regs (loop-invariant, was 32
// ds_read_b128/iter on the CU-shared LDS pipe -> the round-2 bottleneck).
__global__ __launch_bounds__(256, 2) void edge_kernel(const float* __restrict__ proj,
                                                      const int* __restrict__ ei,
                                                      const float* __restrict__ b_lin,
                                                      const float* __restrict__ anchor,
                                                      float* __restrict__ out,
                                                      int nwaves_total) {
    __shared__ float bl[4 * 64];  // per-wave softmax staging (1 KB)

    const int t = threadIdx.x;
    const int l = t & 63;      // lane in wave
    const int wv = t >> 6;     // wave in block
    const int a = l & 31;      // anchor index / softmax lane
    const int hh = l >> 5;     // half-wave -> which edge of the pair

    // anchor rows -> registers, static indexing only (rule #20)
    float4 anc[32];
    {
        const float4* a4 = (const float4*)anchor;
#pragma unroll
        for (int q = 0; q < 32; ++q) anc[q] = a4[q * 32 + a];
    }
    const float bias = b_lin[a];

    const int S = nwaves_total;
    const int NP = N_EDGES / 2;
    int p = blockIdx.x * 4 + wv;

    // depth-2 index prefetch, depth-1 proj prefetch
    int s0 = 0, d0 = 0, s1 = 0, d1 = 0;
    if (p < NP)      { s0 = ei[2 * p + hh];        d0 = ei[N_EDGES + 2 * p + hh]; }
    if (p + S < NP)  { s1 = ei[2 * (p + S) + hh];  d1 = ei[N_EDGES + 2 * (p + S) + hh]; }
    float ps = proj[s0 * 64 + a];
    float pd = proj[d0 * 64 + 32 + a];

    for (; p < NP; p += S) {
        // prefetch indices p+2S
        int s2 = 0, d2 = 0;
        if (p + 2 * S < NP) {
            s2 = ei[2 * (p + 2 * S) + hh];
            d2 = ei[N_EDGES + 2 * (p + 2 * S) + hh];
        }
        // prefetch proj p+S (indices already resident)
        float psn = proj[s1 * 64 + a];
        float pdn = proj[d1 * 64 + 32 + a];

        // ----- current edge -----
        float lg = ps + pd + bias;
        lg = lg >= 0.f ? lg : NEG * lg;

        // softmax over the 32 lanes of this half (xor<32 stays in-half)
        float m = lg;
#pragma unroll
        for (int off = 16; off; off >>= 1) m = fmaxf(m, __shfl_xor(m, off, 64));
        float pe = __expf(lg - m);
        float sm = pe;
#pragma unroll
        for (int off = 16; off; off >>= 1) sm += __shfl_xor(sm, off, 64);
        float bv = pe * __builtin_amdgcn_rcpf(sm);

        bl[wv * 64 + l] = bv;
        asm volatile("s_waitcnt lgkmcnt(0)" ::: "memory");  // DS in-order, wave-lockstep

        // PV: prompt[dims 4a..4a+3] = sum_q b[q] * anchor[q][dims]
        float4 acc = make_float4(0.f, 0.f, 0.f, 0.f);
        const float4* blq = (const float4*)&bl[wv * 64 + hh * 32];
#pragma unroll
        for (int q8 = 0; q8 < 8; ++q8) {
            float4 bq = blq[q8];  // broadcast within half
#pragma unroll
            for (int j = 0; j < 4; ++j) {
                const float bs = (j == 0) ? bq.x : (j == 1) ? bq.y : (j == 2) ? bq.z : bq.w;
                float4 an = anc[q8 * 4 + j];
                acc.x += bs * an.x;
                acc.y += bs * an.y;
                acc.z += bs * an.z;
                acc.w += bs * an.w;
            }
        }
        const int e = 2 * p + hh;
        ((float4*)out)[e * 32 + a] = acc;  // wave writes contiguous 2 KB

        // rotate pipeline
        s1 = s2; d1 = d2;
        ps = psn; pd = pdn;
    }
}

extern "C" void kernel_launch(void* const* d_in, const int* in_sizes, int n_in,
                              void* d_out, int out_size, void* d_ws, size_t ws_size,
                              hipStream_t stream) {
    const float* x = (const float*)d_in[0];
    const int* ei = (const int*)d_in[1];
    // d_in[2] = layer (unused)
    const float* W = (const float*)d_in[3];
    const float* b_lin = (const float*)d_in[4];
    const float* anchor = (const float*)d_in[5];
    float* out = (float*)d_out;
    float* proj = (float*)d_ws;  // 50000*64*4 = 12.8 MB

    proj_kernel<<<(N_NODES + 127) / 128, 256, 0, stream>>>(x, W, proj);

    const int blocksB = 2048;
    edge_kernel<<<blocksB, 256, 0, stream>>>(proj, ei, b_lin, anchor, out, blocksB * 4);
}

// Round 4
// 322.686 us; speedup vs baseline: 1.0018x; 1.0018x over previous
//
#include <hip/hip_runtime.h>

#define N_NODES 50000
#define N_EDGES 400000
#define NA 32
#define NEG 0.01f

// ---------------- Kernel A: per-node projection (unchanged) ----------------
// proj[n][a]    = dot(x[n], W[a][0:128]),  proj[n][32+a] = dot(x[n], W[a][128:256])
__global__ __launch_bounds__(256) void proj_kernel(const float* __restrict__ x,
                                                   const float* __restrict__ W,
                                                   float* __restrict__ proj) {
    __shared__ float Wl[64 * 128];  // 32 KB
    const int t = threadIdx.x;
    for (int i = 0; i < 32; ++i) {
        int idx = i * 256 + t;
        int a = idx >> 7, k = idx & 127;
        Wl[idx] = (a < 32) ? W[a * 256 + k] : W[(a - 32) * 256 + 128 + k];
    }
    __syncthreads();

    const int n0 = blockIdx.x * 128 + (t & 63);
    const int n1 = n0 + 64;
    const int w = t >> 6;
    const int n0c = n0 < N_NODES ? n0 : 0;
    const int n1c = n1 < N_NODES ? n1 : 0;

    const float4* x4 = (const float4*)x;
    float acc0[16], acc1[16];
#pragma unroll
    for (int i = 0; i < 16; ++i) { acc0[i] = 0.f; acc1[i] = 0.f; }

#pragma unroll 1
    for (int kc = 0; kc < 32; ++kc) {
        float4 xv0 = x4[n0c * 32 + kc];
        float4 xv1 = x4[n1c * 32 + kc];
        const float* wbase = &Wl[(w * 16) * 128 + kc * 4];
#pragma unroll
        for (int i = 0; i < 16; ++i) {
            float4 wv = *(const float4*)(wbase + i * 128);  // wave-broadcast
            acc0[i] += xv0.x * wv.x; acc1[i] += xv1.x * wv.x;
            acc0[i] += xv0.y * wv.y; acc1[i] += xv1.y * wv.y;
            acc0[i] += xv0.z * wv.z; acc1[i] += xv1.z * wv.z;
            acc0[i] += xv0.w * wv.w; acc1[i] += xv1.w * wv.w;
        }
    }

    float4* p4 = (float4*)proj;
    if (n0 < N_NODES) {
#pragma unroll
        for (int j = 0; j < 4; ++j)
            p4[n0 * 16 + w * 4 + j] =
                make_float4(acc0[4 * j], acc0[4 * j + 1], acc0[4 * j + 2], acc0[4 * j + 3]);
    }
    if (n1 < N_NODES) {
#pragma unroll
        for (int j = 0; j < 4; ++j)
            p4[n1 * 16 + w * 4 + j] =
                make_float4(acc1[4 * j], acc1[4 * j + 1], acc1[4 * j + 2], acc1[4 * j + 3]);
    }
}

// DPP-based partial-sum step: v += dpp(v); disabled rows add 0 (old=0, bound_ctrl=1).
#define DPP_ADD(v, ctrl, rmask)                                                            \
    v += __int_as_float(__builtin_amdgcn_update_dpp(0, __float_as_int(v), ctrl, rmask, 0xf, true))

// ---------------- Kernel B v3: one edge per wave, lane = dim-pair ----------------
// logit phase: lane l computes logit for anchor a = l&31 (halves duplicate).
// softmax: 64-lane DPP sum (= 2x the 32-anchor sum), no cross-lane swizzles.
// PV: lane l owns output dims {2l, 2l+1}; anchor [32 rows x 2 dims] in 64 VGPRs;
//     b-vector bounced through 128B of LDS, read back as pure broadcasts.
__global__ __launch_bounds__(256) void edge_kernel(const float* __restrict__ proj,
                                                   const int* __restrict__ ei,
                                                   const float* __restrict__ b_lin,
                                                   const float* __restrict__ anchor,
                                                   float* __restrict__ out,
                                                   int nwaves_total) {
    __shared__ float bl[4 * 32];  // per-wave b-vector (512 B)

    const int t = threadIdx.x;
    const int l = t & 63;   // lane
    const int wv = t >> 6;  // wave in block
    const int a = l & 31;   // anchor index for logit phase

    // anchor rows -> regs: anc[q] = anchor[q][2l..2l+1]; coalesced 512B per load
    float2 anc[32];
    {
        const float2* a2 = (const float2*)anchor;
#pragma unroll
        for (int q = 0; q < 32; ++q) anc[q] = a2[q * 64 + l];
    }
    const float bias = b_lin[a];

    const int S = nwaves_total;
    int p = blockIdx.x * 4 + wv;

    // depth-2 index prefetch, depth-1 proj prefetch
    int s0 = 0, d0 = 0, s1 = 0, d1 = 0;
    if (p < N_EDGES)     { s0 = ei[p];     d0 = ei[N_EDGES + p]; }
    if (p + S < N_EDGES) { s1 = ei[p + S]; d1 = ei[N_EDGES + p + S]; }
    float ps = proj[s0 * 64 + a];
    float pd = proj[d0 * 64 + 32 + a];

    for (int e = p; e < N_EDGES; e += S) {
        int s2 = 0, d2 = 0;
        if (e + 2 * S < N_EDGES) { s2 = ei[e + 2 * S]; d2 = ei[N_EDGES + e + 2 * S]; }
        float psn = proj[s1 * 64 + a];
        float pdn = proj[d1 * 64 + 32 + a];

        // ----- logits + exp (no max-subtract: |logit| <~ 5, fp32-safe) -----
        float lg = ps + pd + bias;
        lg = lg >= 0.f ? lg : NEG * lg;
        float pe = __expf(lg);

        // ----- 64-lane DPP sum on the VALU pipe; total = 2 * sum_32 -----
        float r = pe;
        DPP_ADD(r, 0x111, 0xf);  // row_shr:1
        DPP_ADD(r, 0x112, 0xf);  // row_shr:2
        DPP_ADD(r, 0x114, 0xf);  // row_shr:4
        DPP_ADD(r, 0x118, 0xf);  // row_shr:8
        DPP_ADD(r, 0x142, 0xa);  // row_bcast:15 -> rows 1,3
        DPP_ADD(r, 0x143, 0xc);  // row_bcast:31 -> rows 2,3
        float stot = __int_as_float(__builtin_amdgcn_readlane(__float_as_int(r), 63));
        float bv = 2.f * pe * __builtin_amdgcn_rcpf(stot);  // pe / sum_32

        // ----- bounce b through LDS (lower half writes) -----
        if (l < 32) bl[wv * 32 + l] = bv;
        asm volatile("s_waitcnt lgkmcnt(0)" ::: "memory");  // same-wave write->read

        // ----- PV: acc[2 dims] = sum_q b[q] * anc[q]; 4 split accumulators -----
        float2 c0 = {0.f, 0.f}, c1 = {0.f, 0.f}, c2 = {0.f, 0.f}, c3 = {0.f, 0.f};
        const float4* bq4 = (const float4*)&bl[wv * 32];
#pragma unroll
        for (int j = 0; j < 8; ++j) {
            float4 b4 = bq4[j];  // pure broadcast (1 addr across wave)
            float2 a0 = anc[4 * j + 0], a1 = anc[4 * j + 1];
            float2 a2v = anc[4 * j + 2], a3 = anc[4 * j + 3];
            c0.x += b4.x * a0.x; c0.y += b4.x * a0.y;
            c1.x += b4.y * a1.x; c1.y += b4.y * a1.y;
            c2.x += b4.z * a2v.x; c2.y += b4.z * a2v.y;
            c3.x += b4.w * a3.x; c3.y += b4.w * a3.y;
        }
        float2 acc;
        acc.x = (c0.x + c1.x) + (c2.x + c3.x);
        acc.y = (c0.y + c1.y) + (c2.y + c3.y);

        // full-wave coalesced 512B store
        ((float2*)out)[e * 64 + l] = acc;

        s1 = s2; d1 = d2; ps = psn; pd = pdn;
    }
}

extern "C" void kernel_launch(void* const* d_in, const int* in_sizes, int n_in,
                              void* d_out, int out_size, void* d_ws, size_t ws_size,
                              hipStream_t stream) {
    const float* x = (const float*)d_in[0];
    const int* ei = (const int*)d_in[1];
    // d_in[2] = layer (unused)
    const float* W = (const float*)d_in[3];
    const float* b_lin = (const float*)d_in[4];
    const float* anchor = (const float*)d_in[5];
    float* out = (float*)d_out;
    float* proj = (float*)d_ws;  // 12.8 MB

    proj_kernel<<<(N_NODES + 127) / 128, 256, 0, stream>>>(x, W, proj);

    const int blocksB = 2048;
    edge_kernel<<<blocksB, 256, 0, stream>>>(proj, ei, b_lin, anchor, out, blocksB * 4);
}